// Round 6
// baseline (3599.651 us; speedup 1.0000x reference)
//
#include <hip/hip_runtime.h>

#define N_NODES 50000
#define N_PAD   50048
#define N_EDGES 800000
#define NLAYERS 4
#define TPITCH 72

typedef short bf16x8 __attribute__((ext_vector_type(8)));
typedef float f32x4 __attribute__((ext_vector_type(4)));

__device__ __forceinline__ unsigned short f2b(float f) {
  union { float f; unsigned int u; } v; v.f = f;
  unsigned int u = v.u;
  return (unsigned short)((u + 0x7fffu + ((u >> 16) & 1u)) >> 16);
}
__device__ __forceinline__ float b2f(unsigned short s) {
  union { unsigned int u; float f; } v; v.u = ((unsigned int)s) << 16;
  return v.f;
}
__device__ __forceinline__ void split2(float v, unsigned short& hi, unsigned short& lo) {
  hi = f2b(v);
  lo = f2b(v - b2f(hi));
}
__device__ __forceinline__ float silu_f(float x) {
  return x / (1.0f + __expf(-x));
}

#define MFMA3(ah, al, wh, wl, acc)                                        \
  acc = __builtin_amdgcn_mfma_f32_16x16x32_bf16(ah, wh, acc, 0, 0, 0);    \
  acc = __builtin_amdgcn_mfma_f32_16x16x32_bf16(ah, wl, acc, 0, 0, 0);    \
  acc = __builtin_amdgcn_mfma_f32_16x16x32_bf16(al, wh, acc, 0, 0, 0);

// ---------------- weight conversion ----------------
__global__ void k_convW1(const float* __restrict__ eW1, unsigned short* __restrict__ W1h,
                         unsigned short* __restrict__ W1l, float* __restrict__ w1rad) {
  int id = blockIdx.x * 256 + threadIdx.x;
  if (id < NLAYERS * 64) {
    int l = id >> 6, o = id & 63;
    w1rad[id] = eW1[((size_t)l * 193 + 128) * 64 + o];
  }
  if (id >= NLAYERS * 64 * 192) return;
  int k = id % 192; int rem = id / 192; int o = rem & 63; int l = rem >> 6;
  int src = (k < 128) ? k : k + 1;
  float v = eW1[((size_t)l * 193 + src) * 64 + o];
  unsigned short hi, lo; split2(v, hi, lo);
  W1h[id] = hi; W1l[id] = lo;
}
__global__ void k_convT(const float* __restrict__ W, unsigned short* __restrict__ Wh,
                        unsigned short* __restrict__ Wl, int K) {
  int id = blockIdx.x * 256 + threadIdx.x;
  if (id >= NLAYERS * 64 * K) return;
  int k = id % K; int rem = id / K; int o = rem % 64; int l = rem / 64;
  float v = W[((size_t)l * K + k) * 64 + o];
  unsigned short hi, lo; split2(v, hi, lo);
  Wh[id] = hi; Wl[id] = lo;
}

// ---------------- embeddings ----------------
__global__ void k_h0(const float* __restrict__ hin, const float* __restrict__ W,
                     const float* __restrict__ b, unsigned short* __restrict__ hbh,
                     unsigned short* __restrict__ hbl) {
  int id = blockIdx.x * 256 + threadIdx.x;
  if (id >= N_NODES * 64) return;
  int n = id >> 6, j = id & 63;
  float s = b[j];
#pragma unroll
  for (int k = 0; k < 16; k++) s += hin[n * 16 + k] * W[k * 64 + j];
  unsigned short hi, lo; split2(s, hi, lo);
  hbh[id] = hi; hbl[id] = lo;
}
__global__ void k_e0(const float* __restrict__ ea, const float* __restrict__ W,
                     const float* __restrict__ b, unsigned short* __restrict__ ebh,
                     unsigned short* __restrict__ ebl) {
  int id = blockIdx.x * 256 + threadIdx.x;
  if (id >= N_EDGES * 64) return;
  int e = id >> 6, j = id & 63;
  float s = b[j];
#pragma unroll
  for (int k = 0; k < 8; k++) s += ea[e * 8 + k] * W[k * 64 + j];
  unsigned short hi, lo; split2(s, hi, lo);
  ebh[id] = hi; ebl[id] = lo;
}

// ---------------- fused edge kernel (one layer) ----------------
// LDS ~20KB (T and M share one buffer pair) -> 8 blocks/CU = 32 waves/CU,
// matching the compiler's 64-VGPR 8-waves/SIMD scheduling target.
__global__ __launch_bounds__(256, 8) void edge_kernel(
    const unsigned short* __restrict__ hbh, const unsigned short* __restrict__ hbl,
    unsigned short* __restrict__ ebh, unsigned short* __restrict__ ebl,
    const float* __restrict__ xin, float* __restrict__ xout,
    float* __restrict__ agg, const int* __restrict__ eidx,
    const float* __restrict__ emask,
    const unsigned short* __restrict__ W1h, const unsigned short* __restrict__ W1l,
    const float* __restrict__ w1rad,
    const unsigned short* __restrict__ W2h, const unsigned short* __restrict__ W2l,
    const unsigned short* __restrict__ Wch, const unsigned short* __restrict__ Wcl,
    const float* __restrict__ eb1, const float* __restrict__ eb2,
    const float* __restrict__ cb1, const float* __restrict__ cw2) {
  // sXh/sXl hold T during GEMM2, then M during GEMM3 (aliased; barrier-protected)
  __shared__ __attribute__((aligned(16))) unsigned short sXh[64 * TPITCH];
  __shared__ __attribute__((aligned(16))) unsigned short sXl[64 * TPITCH];
  __shared__ float sNdx[64 * 3];
  __shared__ float sRad[64];
  __shared__ float sMask[64];
  __shared__ int sRow[64];

  const int t = threadIdx.x;
  const int eb = blockIdx.x * 64;
  const int lane = t & 63, w = t >> 6;
  const int q = lane >> 4, li = lane & 15;
  const int erow = w * 16 + li;
  const int e = eb + erow;

  const int r0 = eidx[e], c0 = eidx[N_EDGES + e];

  // Preload ALL GEMM1 A-fragments (random gathers) ASAP
  bf16x8 aH[6], aL[6];
  {
    const unsigned short* bh[3] = { hbh + (size_t)r0 * 64, hbh + (size_t)c0 * 64,
                                    ebh + (size_t)e * 64 };
    const unsigned short* bl[3] = { hbl + (size_t)r0 * 64, hbl + (size_t)c0 * 64,
                                    ebl + (size_t)e * 64 };
#pragma unroll
    for (int ch = 0; ch < 3; ch++)
#pragma unroll
      for (int ks = 0; ks < 2; ks++) {
        int k = ks * 32 + q * 8;
        aH[ch * 2 + ks] = *(const bf16x8*)(bh[ch] + k);
        aL[ch * 2 + ks] = *(const bf16x8*)(bl[ch] + k);
      }
  }

  if (t < 64) {
    int ee = eb + t;
    int r = eidx[ee], c = eidx[N_EDGES + ee];
    sRow[t] = r;
    sMask[t] = emask[ee];
    float dx0 = xin[r * 3 + 0] - xin[c * 3 + 0];
    float dx1 = xin[r * 3 + 1] - xin[c * 3 + 1];
    float dx2 = xin[r * 3 + 2] - xin[c * 3 + 2];
    float rad = dx0 * dx0 + dx1 * dx1 + dx2 * dx2;
    float inv = 1.0f / (sqrtf(rad) + 1.0f);
    sNdx[t * 3 + 0] = dx0 * inv; sNdx[t * 3 + 1] = dx1 * inv; sNdx[t * 3 + 2] = dx2 * inv;
    sRad[t] = rad;
  }

  f32x4 acc[4];
  const f32x4 zero4 = {0.f, 0.f, 0.f, 0.f};
#pragma unroll
  for (int ct = 0; ct < 4; ct++) acc[ct] = zero4;

  // GEMM1: (ch,ks) groups, ct-inner
#pragma unroll
  for (int ch = 0; ch < 3; ch++)
#pragma unroll
    for (int ks = 0; ks < 2; ks++) {
      int k = ks * 32 + q * 8;
      bf16x8 wH[4], wL[4];
#pragma unroll
      for (int ct = 0; ct < 4; ct++) {
        size_t wo = (size_t)(ct * 16 + li) * 192 + ch * 64 + k;
        wH[ct] = *(const bf16x8*)(W1h + wo);
        wL[ct] = *(const bf16x8*)(W1l + wo);
      }
#pragma unroll
      for (int ct = 0; ct < 4; ct++) {
        MFMA3(aH[ch * 2 + ks], aL[ch * 2 + ks], wH[ct], wL[ct], acc[ct]);
      }
    }
  __syncthreads();  // sRad ready; also orders sX writes below

  // rank-1 radial (fp32) + bias + silu -> sX (holds T)
#pragma unroll
  for (int ct = 0; ct < 4; ct++) {
    float bias = eb1[ct * 16 + li];
    float wr = w1rad[ct * 16 + li];
#pragma unroll
    for (int r = 0; r < 4; r++) {
      int el = w * 16 + q * 4 + r;
      float v = silu_f(acc[ct][r] + bias + sRad[el] * wr);
      unsigned short hi, lo; split2(v, hi, lo);
      sXh[el * TPITCH + ct * 16 + li] = hi;
      sXl[el * TPITCH + ct * 16 + li] = lo;
    }
  }
  __syncthreads();  // T visible to all waves

  // GEMM2 -> m ; read T frags, then barrier so sX can be reused for M
  bf16x8 tH[2], tL[2];
#pragma unroll
  for (int ks = 0; ks < 2; ks++) {
    int kb = ks * 32 + q * 8;
    tH[ks] = *(const bf16x8*)(sXh + erow * TPITCH + kb);
    tL[ks] = *(const bf16x8*)(sXl + erow * TPITCH + kb);
  }
  __syncthreads();  // all waves done reading T; sX reusable

#pragma unroll
  for (int ct = 0; ct < 4; ct++) acc[ct] = zero4;
#pragma unroll
  for (int ks = 0; ks < 2; ks++) {
    int kb = ks * 32 + q * 8;
    bf16x8 wH[4], wL[4];
#pragma unroll
    for (int ct = 0; ct < 4; ct++) {
      size_t wo = (size_t)(ct * 16 + li) * 64 + kb;
      wH[ct] = *(const bf16x8*)(W2h + wo);
      wL[ct] = *(const bf16x8*)(W2l + wo);
    }
#pragma unroll
    for (int ct = 0; ct < 4; ct++) {
      MFMA3(tH[ks], tL[ks], wH[ct], wL[ct], acc[ct]);
    }
  }
#pragma unroll
  for (int ct = 0; ct < 4; ct++) {
    float bias = eb2[ct * 16 + li];
#pragma unroll
    for (int r = 0; r < 4; r++) {
      int el = w * 16 + q * 4 + r;
      float v = silu_f(acc[ct][r] + bias) * sMask[el];
      unsigned short hi, lo; split2(v, hi, lo);
      sXh[el * TPITCH + ct * 16 + li] = hi;
      sXl[el * TPITCH + ct * 16 + li] = lo;
      atomicAdd(&agg[(size_t)sRow[el] * 64 + ct * 16 + li], v);
    }
  }
  __syncthreads();  // M visible to all waves

  // write m hi/lo back to ebuf (coalesced)
  {
    int el = t >> 2, part = t & 3;
    const uint4* sh = (const uint4*)(sXh + el * TPITCH + part * 16);
    const uint4* sl = (const uint4*)(sXl + el * TPITCH + part * 16);
    uint4* dh = (uint4*)(ebh + (size_t)(eb + el) * 64 + part * 16);
    uint4* dl = (uint4*)(ebl + (size_t)(eb + el) * 64 + part * 16);
    dh[0] = sh[0]; dh[1] = sh[1];
    dl[0] = sl[0]; dl[1] = sl[1];
  }

  // GEMM3: u = silu(m@cW1+cb1), p = u . cw2
#pragma unroll
  for (int ct = 0; ct < 4; ct++) acc[ct] = zero4;
  {
    bf16x8 mH[2], mL[2];
#pragma unroll
    for (int ks = 0; ks < 2; ks++) {
      int kb = ks * 32 + q * 8;
      mH[ks] = *(const bf16x8*)(sXh + erow * TPITCH + kb);
      mL[ks] = *(const bf16x8*)(sXl + erow * TPITCH + kb);
    }
#pragma unroll
    for (int ks = 0; ks < 2; ks++) {
      int kb = ks * 32 + q * 8;
      bf16x8 wH[4], wL[4];
#pragma unroll
      for (int ct = 0; ct < 4; ct++) {
        size_t wo = (size_t)(ct * 16 + li) * 64 + kb;
        wH[ct] = *(const bf16x8*)(Wch + wo);
        wL[ct] = *(const bf16x8*)(Wcl + wo);
      }
#pragma unroll
      for (int ct = 0; ct < 4; ct++) {
        MFMA3(mH[ks], mL[ks], wH[ct], wL[ct], acc[ct]);
      }
    }
  }
  float p[4] = {0.f, 0.f, 0.f, 0.f};
#pragma unroll
  for (int ct = 0; ct < 4; ct++) {
    float bias = cb1[ct * 16 + li];
    float wv = cw2[ct * 16 + li];
#pragma unroll
    for (int r = 0; r < 4; r++) p[r] += silu_f(acc[ct][r] + bias) * wv;
  }
#pragma unroll
  for (int m = 1; m < 16; m <<= 1) {
#pragma unroll
    for (int r = 0; r < 4; r++) p[r] += __shfl_xor(p[r], m, 64);
  }
  if (li < 3) {
#pragma unroll
    for (int r = 0; r < 4; r++) {
      int el = w * 16 + q * 4 + r;
      atomicAdd(&xout[(size_t)sRow[el] * 3 + li], sNdx[el * 3 + li] * p[r]);
    }
  }
}

// ---------------- node kernel (one layer) ----------------
__global__ __launch_bounds__(256, 8) void node_kernel(
    unsigned short* __restrict__ hbh, unsigned short* __restrict__ hbl,
    const float* __restrict__ agg,
    float* __restrict__ xout, const float* __restrict__ nmask,
    const unsigned short* __restrict__ Wn1h, const unsigned short* __restrict__ Wn1l,
    const unsigned short* __restrict__ Wn2h, const unsigned short* __restrict__ Wn2l,
    const float* __restrict__ nb1, const float* __restrict__ nb2) {
  __shared__ __attribute__((aligned(16))) unsigned short sTh[64 * TPITCH];
  __shared__ __attribute__((aligned(16))) unsigned short sTl[64 * TPITCH];
  const int t = threadIdx.x;
  const int nb = blockIdx.x * 64;
  const int lane = t & 63, w = t >> 6;
  const int q = lane >> 4, li = lane & 15;
  const int nrow = w * 16 + li;
  const size_t node = (size_t)nb + nrow;  // pad rows read garbage; outputs guarded

  // Preload A-fragments
  bf16x8 aH[2], aL[2], gH[2], gL[2];
#pragma unroll
  for (int ks = 0; ks < 2; ks++) {
    int k = ks * 32 + q * 8;
    aH[ks] = *(const bf16x8*)(hbh + node * 64 + k);
    aL[ks] = *(const bf16x8*)(hbl + node * 64 + k);
    const float4* ap = (const float4*)(agg + node * 64 + k);
    float4 a0 = ap[0], a1 = ap[1];
    float av[8] = {a0.x, a0.y, a0.z, a0.w, a1.x, a1.y, a1.z, a1.w};
    unsigned short* ph = (unsigned short*)&gH[ks];
    unsigned short* pl = (unsigned short*)&gL[ks];
#pragma unroll
    for (int j = 0; j < 8; j++) split2(av[j], ph[j], pl[j]);
  }

  if (t < 192) {
    int n = nb + t / 3, c = t % 3;
    if (n < N_NODES) xout[(size_t)n * 3 + c] *= nmask[n];
  }

  f32x4 acc[4];
  const f32x4 zero4 = {0.f, 0.f, 0.f, 0.f};
#pragma unroll
  for (int ct = 0; ct < 4; ct++) acc[ct] = zero4;

  // chunk h (k 0..63)
#pragma unroll
  for (int ks = 0; ks < 2; ks++) {
    int k = ks * 32 + q * 8;
    bf16x8 wH[4], wL[4];
#pragma unroll
    for (int ct = 0; ct < 4; ct++) {
      size_t wo = (size_t)(ct * 16 + li) * 128 + k;
      wH[ct] = *(const bf16x8*)(Wn1h + wo);
      wL[ct] = *(const bf16x8*)(Wn1l + wo);
    }
#pragma unroll
    for (int ct = 0; ct < 4; ct++) {
      MFMA3(aH[ks], aL[ks], wH[ct], wL[ct], acc[ct]);
    }
  }
  // chunk agg (k 64..127)
#pragma unroll
  for (int ks = 0; ks < 2; ks++) {
    int k = ks * 32 + q * 8;
    bf16x8 wH[4], wL[4];
#pragma unroll
    for (int ct = 0; ct < 4; ct++) {
      size_t wo = (size_t)(ct * 16 + li) * 128 + 64 + k;
      wH[ct] = *(const bf16x8*)(Wn1h + wo);
      wL[ct] = *(const bf16x8*)(Wn1l + wo);
    }
#pragma unroll
    for (int ct = 0; ct < 4; ct++) {
      MFMA3(gH[ks], gL[ks], wH[ct], wL[ct], acc[ct]);
    }
  }
#pragma unroll
  for (int ct = 0; ct < 4; ct++) {
    float bias = nb1[ct * 16 + li];
#pragma unroll
    for (int r = 0; r < 4; r++) {
      int nl = w * 16 + q * 4 + r;
      float v = silu_f(acc[ct][r] + bias);
      unsigned short hi, lo; split2(v, hi, lo);
      sTh[nl * TPITCH + ct * 16 + li] = hi;
      sTl[nl * TPITCH + ct * 16 + li] = lo;
    }
  }
  __syncthreads();

#pragma unroll
  for (int ct = 0; ct < 4; ct++) acc[ct] = zero4;
  {
    bf16x8 tH[2], tL[2];
#pragma unroll
    for (int ks = 0; ks < 2; ks++) {
      int kb = ks * 32 + q * 8;
      tH[ks] = *(const bf16x8*)(sTh + nrow * TPITCH + kb);
      tL[ks] = *(const bf16x8*)(sTl + nrow * TPITCH + kb);
    }
#pragma unroll
    for (int ks = 0; ks < 2; ks++) {
      int kb = ks * 32 + q * 8;
      bf16x8 wH[4], wL[4];
#pragma unroll
      for (int ct = 0; ct < 4; ct++) {
        size_t wo = (size_t)(ct * 16 + li) * 64 + kb;
        wH[ct] = *(const bf16x8*)(Wn2h + wo);
        wL[ct] = *(const bf16x8*)(Wn2l + wo);
      }
#pragma unroll
      for (int ct = 0; ct < 4; ct++) {
        MFMA3(tH[ks], tL[ks], wH[ct], wL[ct], acc[ct]);
      }
    }
  }
#pragma unroll
  for (int ct = 0; ct < 4; ct++) {
    float bias = nb2[ct * 16 + li];
#pragma unroll
    for (int r = 0; r < 4; r++) {
      int nd = nb + w * 16 + q * 4 + r;
      if (nd < N_NODES) {
        float nm = nmask[nd];
        size_t o = (size_t)nd * 64 + ct * 16 + li;
        float hv = b2f(hbh[o]) + b2f(hbl[o]);
        float v = (hv + acc[ct][r] + bias) * nm;
        unsigned short hi, lo; split2(v, hi, lo);
        hbh[o] = hi; hbl[o] = lo;
      }
    }
  }
}

// ---------------- output heads ----------------
__global__ void k_hout(const unsigned short* __restrict__ hbh,
                       const unsigned short* __restrict__ hbl,
                       const float* __restrict__ W, const float* __restrict__ b,
                       const float* __restrict__ nmask, float* __restrict__ out) {
  int id = blockIdx.x * 256 + threadIdx.x;
  if (id >= N_NODES * 16) return;
  int n = id >> 4, j = id & 15;
  float s = b[j];
#pragma unroll
  for (int k = 0; k < 64; k++) {
    float hv = b2f(hbh[(size_t)n * 64 + k]) + b2f(hbl[(size_t)n * 64 + k]);
    s += hv * W[k * 16 + j];
  }
  out[id] = s * nmask[n];
}
__global__ __launch_bounds__(256) void k_eout(const unsigned short* __restrict__ ebh,
                       const unsigned short* __restrict__ ebl,
                       const float* __restrict__ W, const float* __restrict__ b,
                       const float* __restrict__ emask, float* __restrict__ out) {
  __shared__ float sW[512];
  __shared__ float sB[8];
  int t = threadIdx.x;
  sW[t] = W[t]; sW[t + 256] = W[t + 256];
  if (t < 8) sB[t] = b[t];
  __syncthreads();
  int e = blockIdx.x * 256 + t;
  if (e >= N_EDGES) return;
  float accs[8];
#pragma unroll
  for (int j = 0; j < 8; j++) accs[j] = sB[j];
  const uint4* rh = (const uint4*)(ebh + (size_t)e * 64);
  const uint4* rl = (const uint4*)(ebl + (size_t)e * 64);
#pragma unroll
  for (int i = 0; i < 8; i++) {
    uint4 vh = rh[i], vl = rl[i];
    unsigned int uh[4] = {vh.x, vh.y, vh.z, vh.w};
    unsigned int ul[4] = {vl.x, vl.y, vl.z, vl.w};
#pragma unroll
    for (int pp = 0; pp < 4; pp++) {
      float lo = b2f((unsigned short)(uh[pp] & 0xffffu)) + b2f((unsigned short)(ul[pp] & 0xffffu));
      float hi = b2f((unsigned short)(uh[pp] >> 16)) + b2f((unsigned short)(ul[pp] >> 16));
      int k = i * 8 + pp * 2;
#pragma unroll
      for (int j = 0; j < 8; j++)
        accs[j] += lo * sW[k * 8 + j] + hi * sW[(k + 1) * 8 + j];
    }
  }
  float em = emask[e];
#pragma unroll
  for (int j = 0; j < 8; j++) out[(size_t)e * 8 + j] = accs[j] * em;
}

extern "C" void kernel_launch(void* const* d_in, const int* in_sizes, int n_in,
                              void* d_out, int out_size, void* d_ws, size_t ws_size,
                              hipStream_t stream) {
  (void)in_sizes; (void)n_in; (void)out_size; (void)ws_size;
  const float* in_h   = (const float*)d_in[0];
  const float* in_x   = (const float*)d_in[1];
  const float* in_ea  = (const float*)d_in[2];
  const float* nmask  = (const float*)d_in[3];
  const float* emask  = (const float*)d_in[4];
  const float* Wn_in  = (const float*)d_in[5];
  const float* bn_in  = (const float*)d_in[6];
  const float* Wn_out = (const float*)d_in[7];
  const float* bn_out = (const float*)d_in[8];
  const float* We_in  = (const float*)d_in[9];
  const float* be_in  = (const float*)d_in[10];
  const float* We_out = (const float*)d_in[11];
  const float* be_out = (const float*)d_in[12];
  const float* eW1    = (const float*)d_in[13];
  const float* eb1    = (const float*)d_in[14];
  const float* eW2    = (const float*)d_in[15];
  const float* eb2    = (const float*)d_in[16];
  const float* nW1    = (const float*)d_in[17];
  const float* nb1    = (const float*)d_in[18];
  const float* nW2    = (const float*)d_in[19];
  const float* nb2    = (const float*)d_in[20];
  const float* cW1    = (const float*)d_in[21];
  const float* cb1    = (const float*)d_in[22];
  const float* cW2    = (const float*)d_in[23];
  const int*   eidx   = (const int*)d_in[24];

  char* ws = (char*)d_ws;
  size_t off = 0;
  auto alloc = [&](size_t bytes) {
    size_t o = off; off = (off + bytes + 255) & ~(size_t)255; return (void*)(ws + o);
  };
  unsigned short* hbh  = (unsigned short*)alloc((size_t)N_PAD * 64 * 2);
  unsigned short* hbl  = (unsigned short*)alloc((size_t)N_PAD * 64 * 2);
  unsigned short* ebh  = (unsigned short*)alloc((size_t)N_EDGES * 64 * 2);
  unsigned short* ebl  = (unsigned short*)alloc((size_t)N_EDGES * 64 * 2);
  float* agg           = (float*)alloc((size_t)N_PAD * 64 * 4);
  float* xb0           = (float*)alloc((size_t)N_NODES * 3 * 4);
  float* xb1           = (float*)alloc((size_t)N_NODES * 3 * 4);
  unsigned short* W1h  = (unsigned short*)alloc((size_t)NLAYERS * 64 * 192 * 2);
  unsigned short* W1l  = (unsigned short*)alloc((size_t)NLAYERS * 64 * 192 * 2);
  float* w1rad         = (float*)alloc((size_t)NLAYERS * 64 * 4);
  unsigned short* W2h  = (unsigned short*)alloc((size_t)NLAYERS * 64 * 64 * 2);
  unsigned short* W2l  = (unsigned short*)alloc((size_t)NLAYERS * 64 * 64 * 2);
  unsigned short* Wch  = (unsigned short*)alloc((size_t)NLAYERS * 64 * 64 * 2);
  unsigned short* Wcl  = (unsigned short*)alloc((size_t)NLAYERS * 64 * 64 * 2);
  unsigned short* Wn1h = (unsigned short*)alloc((size_t)NLAYERS * 64 * 128 * 2);
  unsigned short* Wn1l = (unsigned short*)alloc((size_t)NLAYERS * 64 * 128 * 2);
  unsigned short* Wn2h = (unsigned short*)alloc((size_t)NLAYERS * 64 * 64 * 2);
  unsigned short* Wn2l = (unsigned short*)alloc((size_t)NLAYERS * 64 * 64 * 2);

  k_convW1<<<(NLAYERS * 64 * 192 + 255) / 256, 256, 0, stream>>>(eW1, W1h, W1l, w1rad);
  k_convT<<<(NLAYERS * 64 * 64 + 255) / 256, 256, 0, stream>>>(eW2, W2h, W2l, 64);
  k_convT<<<(NLAYERS * 64 * 64 + 255) / 256, 256, 0, stream>>>(cW1, Wch, Wcl, 64);
  k_convT<<<(NLAYERS * 64 * 128 + 255) / 256, 256, 0, stream>>>(nW1, Wn1h, Wn1l, 128);
  k_convT<<<(NLAYERS * 64 * 64 + 255) / 256, 256, 0, stream>>>(nW2, Wn2h, Wn2l, 64);

  k_h0<<<(N_NODES * 64 + 255) / 256, 256, 0, stream>>>(in_h, Wn_in, bn_in, hbh, hbl);
  k_e0<<<(N_EDGES * 64 + 255) / 256, 256, 0, stream>>>(in_ea, We_in, be_in, ebh, ebl);
  hipMemcpyAsync(xb0, in_x, (size_t)N_NODES * 3 * 4, hipMemcpyDeviceToDevice, stream);

  for (int l = 0; l < NLAYERS; l++) {
    float* xi = (l & 1) ? xb1 : xb0;
    float* xo = (l & 1) ? xb0 : xb1;
    hipMemsetAsync(agg, 0, (size_t)N_NODES * 64 * 4, stream);
    hipMemcpyAsync(xo, xi, (size_t)N_NODES * 3 * 4, hipMemcpyDeviceToDevice, stream);
    edge_kernel<<<N_EDGES / 64, 256, 0, stream>>>(
        hbh, hbl, ebh, ebl, xi, xo, agg, eidx, emask,
        W1h + (size_t)l * 64 * 192, W1l + (size_t)l * 64 * 192, w1rad + (size_t)l * 64,
        W2h + (size_t)l * 64 * 64, W2l + (size_t)l * 64 * 64,
        Wch + (size_t)l * 64 * 64, Wcl + (size_t)l * 64 * 64,
        eb1 + l * 64, eb2 + l * 64, cb1 + l * 64, cW2 + l * 64);
    node_kernel<<<(N_NODES + 63) / 64, 256, 0, stream>>>(
        hbh, hbl, agg, xo, nmask,
        Wn1h + (size_t)l * 64 * 128, Wn1l + (size_t)l * 64 * 128,
        Wn2h + (size_t)l * 64 * 64, Wn2l + (size_t)l * 64 * 64,
        nb1 + l * 64, nb2 + l * 64);
  }

  float* out = (float*)d_out;
  k_hout<<<(N_NODES * 16 + 255) / 256, 256, 0, stream>>>(hbh, hbl, Wn_out, bn_out, nmask, out);
  k_eout<<<N_EDGES / 256, 256, 0, stream>>>(ebh, ebl, We_out, be_out, emask, out + 950000);
  hipMemcpyAsync(out + 800000, xb0, (size_t)N_NODES * 3 * 4, hipMemcpyDeviceToDevice, stream);
}

// Round 7
// 2735.544 us; speedup vs baseline: 1.3159x; 1.3159x over previous
//
#include <hip/hip_runtime.h>

#define N_NODES 50000
#define N_PAD   50048
#define N_EDGES 800000
#define NLAYERS 4
#define TPITCH 72

typedef short bf16x8 __attribute__((ext_vector_type(8)));
typedef float f32x4 __attribute__((ext_vector_type(4)));

__device__ __forceinline__ unsigned short f2b(float f) {
  union { float f; unsigned int u; } v; v.f = f;
  unsigned int u = v.u;
  return (unsigned short)((u + 0x7fffu + ((u >> 16) & 1u)) >> 16);
}
__device__ __forceinline__ float b2f(unsigned short s) {
  union { unsigned int u; float f; } v; v.u = ((unsigned int)s) << 16;
  return v.f;
}
__device__ __forceinline__ void split2(float v, unsigned short& hi, unsigned short& lo) {
  hi = f2b(v);
  lo = f2b(v - b2f(hi));
}
__device__ __forceinline__ float silu_f(float x) {
  return x / (1.0f + __expf(-x));
}

#define MFMA3(ah, al, wh, wl, acc)                                        \
  acc = __builtin_amdgcn_mfma_f32_16x16x32_bf16(ah, wh, acc, 0, 0, 0);    \
  acc = __builtin_amdgcn_mfma_f32_16x16x32_bf16(ah, wl, acc, 0, 0, 0);    \
  acc = __builtin_amdgcn_mfma_f32_16x16x32_bf16(al, wh, acc, 0, 0, 0);

// ---------------- weight conversion ----------------
__global__ void k_convW1(const float* __restrict__ eW1, unsigned short* __restrict__ W1h,
                         unsigned short* __restrict__ W1l, float* __restrict__ w1rad) {
  int id = blockIdx.x * 256 + threadIdx.x;
  if (id < NLAYERS * 64) {
    int l = id >> 6, o = id & 63;
    w1rad[id] = eW1[((size_t)l * 193 + 128) * 64 + o];
  }
  if (id >= NLAYERS * 64 * 192) return;
  int k = id % 192; int rem = id / 192; int o = rem & 63; int l = rem >> 6;
  int src = (k < 128) ? k : k + 1;
  float v = eW1[((size_t)l * 193 + src) * 64 + o];
  unsigned short hi, lo; split2(v, hi, lo);
  W1h[id] = hi; W1l[id] = lo;
}
__global__ void k_convT(const float* __restrict__ W, unsigned short* __restrict__ Wh,
                        unsigned short* __restrict__ Wl, int K) {
  int id = blockIdx.x * 256 + threadIdx.x;
  if (id >= NLAYERS * 64 * K) return;
  int k = id % K; int rem = id / K; int o = rem % 64; int l = rem / 64;
  float v = W[((size_t)l * K + k) * 64 + o];
  unsigned short hi, lo; split2(v, hi, lo);
  Wh[id] = hi; Wl[id] = lo;
}

// ---------------- embeddings ----------------
__global__ void k_h0(const float* __restrict__ hin, const float* __restrict__ W,
                     const float* __restrict__ b, unsigned short* __restrict__ hbh,
                     unsigned short* __restrict__ hbl) {
  int id = blockIdx.x * 256 + threadIdx.x;
  if (id >= N_NODES * 64) return;
  int n = id >> 6, j = id & 63;
  float s = b[j];
#pragma unroll
  for (int k = 0; k < 16; k++) s += hin[n * 16 + k] * W[k * 64 + j];
  unsigned short hi, lo; split2(s, hi, lo);
  hbh[id] = hi; hbl[id] = lo;
}
__global__ void k_e0(const float* __restrict__ ea, const float* __restrict__ W,
                     const float* __restrict__ b, unsigned short* __restrict__ ebh,
                     unsigned short* __restrict__ ebl) {
  int id = blockIdx.x * 256 + threadIdx.x;
  if (id >= N_EDGES * 64) return;
  int e = id >> 6, j = id & 63;
  float s = b[j];
#pragma unroll
  for (int k = 0; k < 8; k++) s += ea[e * 8 + k] * W[k * 64 + j];
  unsigned short hi, lo; split2(s, hi, lo);
  ebh[id] = hi; ebl[id] = lo;
}

// ---------------- fused edge kernel (one layer) ----------------
// LDS ~20KB (T/M aliased) -> 8 blocks/CU possible. launch_bounds(256,4):
// VGPR cap 128; compiler historically picks 64 -> HW reaches 8 blocks/CU
// WITHOUT the (256,8) spill disaster of R6 (VGPR=32, +1.1GB scratch traffic).
__global__ __launch_bounds__(256, 4) void edge_kernel(
    const unsigned short* __restrict__ hbh, const unsigned short* __restrict__ hbl,
    unsigned short* __restrict__ ebh, unsigned short* __restrict__ ebl,
    const float* __restrict__ xin, float* __restrict__ xout,
    float* __restrict__ agg, const int* __restrict__ eidx,
    const float* __restrict__ emask,
    const unsigned short* __restrict__ W1h, const unsigned short* __restrict__ W1l,
    const float* __restrict__ w1rad,
    const unsigned short* __restrict__ W2h, const unsigned short* __restrict__ W2l,
    const unsigned short* __restrict__ Wch, const unsigned short* __restrict__ Wcl,
    const float* __restrict__ eb1, const float* __restrict__ eb2,
    const float* __restrict__ cb1, const float* __restrict__ cw2) {
  // sXh/sXl hold T during GEMM2, then M during GEMM3 (aliased; barrier-protected)
  __shared__ __attribute__((aligned(16))) unsigned short sXh[64 * TPITCH];
  __shared__ __attribute__((aligned(16))) unsigned short sXl[64 * TPITCH];
  __shared__ float sNdx[64 * 3];
  __shared__ float sRad[64];
  __shared__ float sMask[64];
  __shared__ int sRow[64];

  const int t = threadIdx.x;
  const int eb = blockIdx.x * 64;
  const int lane = t & 63, w = t >> 6;
  const int q = lane >> 4, li = lane & 15;
  const int erow = w * 16 + li;
  const int e = eb + erow;

  const int r0 = eidx[e], c0 = eidx[N_EDGES + e];

  // Preload ALL GEMM1 A-fragments (random gathers) ASAP
  bf16x8 aH[6], aL[6];
  {
    const unsigned short* bh[3] = { hbh + (size_t)r0 * 64, hbh + (size_t)c0 * 64,
                                    ebh + (size_t)e * 64 };
    const unsigned short* bl[3] = { hbl + (size_t)r0 * 64, hbl + (size_t)c0 * 64,
                                    ebl + (size_t)e * 64 };
#pragma unroll
    for (int ch = 0; ch < 3; ch++)
#pragma unroll
      for (int ks = 0; ks < 2; ks++) {
        int k = ks * 32 + q * 8;
        aH[ch * 2 + ks] = *(const bf16x8*)(bh[ch] + k);
        aL[ch * 2 + ks] = *(const bf16x8*)(bl[ch] + k);
      }
  }

  if (t < 64) {
    int ee = eb + t;
    int r = eidx[ee], c = eidx[N_EDGES + ee];
    sRow[t] = r;
    sMask[t] = emask[ee];
    float dx0 = xin[r * 3 + 0] - xin[c * 3 + 0];
    float dx1 = xin[r * 3 + 1] - xin[c * 3 + 1];
    float dx2 = xin[r * 3 + 2] - xin[c * 3 + 2];
    float rad = dx0 * dx0 + dx1 * dx1 + dx2 * dx2;
    float inv = 1.0f / (sqrtf(rad) + 1.0f);
    sNdx[t * 3 + 0] = dx0 * inv; sNdx[t * 3 + 1] = dx1 * inv; sNdx[t * 3 + 2] = dx2 * inv;
    sRad[t] = rad;
  }

  f32x4 acc[4];
  const f32x4 zero4 = {0.f, 0.f, 0.f, 0.f};
#pragma unroll
  for (int ct = 0; ct < 4; ct++) acc[ct] = zero4;

  // GEMM1: (ch,ks) groups, ct-inner
#pragma unroll
  for (int ch = 0; ch < 3; ch++)
#pragma unroll
    for (int ks = 0; ks < 2; ks++) {
      int k = ks * 32 + q * 8;
      bf16x8 wH[4], wL[4];
#pragma unroll
      for (int ct = 0; ct < 4; ct++) {
        size_t wo = (size_t)(ct * 16 + li) * 192 + ch * 64 + k;
        wH[ct] = *(const bf16x8*)(W1h + wo);
        wL[ct] = *(const bf16x8*)(W1l + wo);
      }
#pragma unroll
      for (int ct = 0; ct < 4; ct++) {
        MFMA3(aH[ch * 2 + ks], aL[ch * 2 + ks], wH[ct], wL[ct], acc[ct]);
      }
    }
  __syncthreads();  // sRad ready; also orders sX writes below

  // rank-1 radial (fp32) + bias + silu -> sX (holds T)
#pragma unroll
  for (int ct = 0; ct < 4; ct++) {
    float bias = eb1[ct * 16 + li];
    float wr = w1rad[ct * 16 + li];
#pragma unroll
    for (int r = 0; r < 4; r++) {
      int el = w * 16 + q * 4 + r;
      float v = silu_f(acc[ct][r] + bias + sRad[el] * wr);
      unsigned short hi, lo; split2(v, hi, lo);
      sXh[el * TPITCH + ct * 16 + li] = hi;
      sXl[el * TPITCH + ct * 16 + li] = lo;
    }
  }
  __syncthreads();  // T visible to all waves

  // GEMM2 -> m ; read T frags, then barrier so sX can be reused for M
  bf16x8 tH[2], tL[2];
#pragma unroll
  for (int ks = 0; ks < 2; ks++) {
    int kb = ks * 32 + q * 8;
    tH[ks] = *(const bf16x8*)(sXh + erow * TPITCH + kb);
    tL[ks] = *(const bf16x8*)(sXl + erow * TPITCH + kb);
  }
  __syncthreads();  // all waves done reading T; sX reusable

#pragma unroll
  for (int ct = 0; ct < 4; ct++) acc[ct] = zero4;
#pragma unroll
  for (int ks = 0; ks < 2; ks++) {
    int kb = ks * 32 + q * 8;
    bf16x8 wH[4], wL[4];
#pragma unroll
    for (int ct = 0; ct < 4; ct++) {
      size_t wo = (size_t)(ct * 16 + li) * 64 + kb;
      wH[ct] = *(const bf16x8*)(W2h + wo);
      wL[ct] = *(const bf16x8*)(W2l + wo);
    }
#pragma unroll
    for (int ct = 0; ct < 4; ct++) {
      MFMA3(tH[ks], tL[ks], wH[ct], wL[ct], acc[ct]);
    }
  }
#pragma unroll
  for (int ct = 0; ct < 4; ct++) {
    float bias = eb2[ct * 16 + li];
#pragma unroll
    for (int r = 0; r < 4; r++) {
      int el = w * 16 + q * 4 + r;
      float v = silu_f(acc[ct][r] + bias) * sMask[el];
      unsigned short hi, lo; split2(v, hi, lo);
      sXh[el * TPITCH + ct * 16 + li] = hi;
      sXl[el * TPITCH + ct * 16 + li] = lo;
      atomicAdd(&agg[(size_t)sRow[el] * 64 + ct * 16 + li], v);
    }
  }
  __syncthreads();  // M visible to all waves

  // write m hi/lo back to ebuf (coalesced)
  {
    int el = t >> 2, part = t & 3;
    const uint4* sh = (const uint4*)(sXh + el * TPITCH + part * 16);
    const uint4* sl = (const uint4*)(sXl + el * TPITCH + part * 16);
    uint4* dh = (uint4*)(ebh + (size_t)(eb + el) * 64 + part * 16);
    uint4* dl = (uint4*)(ebl + (size_t)(eb + el) * 64 + part * 16);
    dh[0] = sh[0]; dh[1] = sh[1];
    dl[0] = sl[0]; dl[1] = sl[1];
  }

  // GEMM3: u = silu(m@cW1+cb1), p = u . cw2
#pragma unroll
  for (int ct = 0; ct < 4; ct++) acc[ct] = zero4;
  {
    bf16x8 mH[2], mL[2];
#pragma unroll
    for (int ks = 0; ks < 2; ks++) {
      int kb = ks * 32 + q * 8;
      mH[ks] = *(const bf16x8*)(sXh + erow * TPITCH + kb);
      mL[ks] = *(const bf16x8*)(sXl + erow * TPITCH + kb);
    }
#pragma unroll
    for (int ks = 0; ks < 2; ks++) {
      int kb = ks * 32 + q * 8;
      bf16x8 wH[4], wL[4];
#pragma unroll
      for (int ct = 0; ct < 4; ct++) {
        size_t wo = (size_t)(ct * 16 + li) * 64 + kb;
        wH[ct] = *(const bf16x8*)(Wch + wo);
        wL[ct] = *(const bf16x8*)(Wcl + wo);
      }
#pragma unroll
      for (int ct = 0; ct < 4; ct++) {
        MFMA3(mH[ks], mL[ks], wH[ct], wL[ct], acc[ct]);
      }
    }
  }
  float p[4] = {0.f, 0.f, 0.f, 0.f};
#pragma unroll
  for (int ct = 0; ct < 4; ct++) {
    float bias = cb1[ct * 16 + li];
    float wv = cw2[ct * 16 + li];
#pragma unroll
    for (int r = 0; r < 4; r++) p[r] += silu_f(acc[ct][r] + bias) * wv;
  }
#pragma unroll
  for (int m = 1; m < 16; m <<= 1) {
#pragma unroll
    for (int r = 0; r < 4; r++) p[r] += __shfl_xor(p[r], m, 64);
  }
  if (li < 3) {
#pragma unroll
    for (int r = 0; r < 4; r++) {
      int el = w * 16 + q * 4 + r;
      atomicAdd(&xout[(size_t)sRow[el] * 3 + li], sNdx[el * 3 + li] * p[r]);
    }
  }
}

// ---------------- node kernel (one layer) ----------------
__global__ __launch_bounds__(256, 4) void node_kernel(
    unsigned short* __restrict__ hbh, unsigned short* __restrict__ hbl,
    const float* __restrict__ agg,
    float* __restrict__ xout, const float* __restrict__ nmask,
    const unsigned short* __restrict__ Wn1h, const unsigned short* __restrict__ Wn1l,
    const unsigned short* __restrict__ Wn2h, const unsigned short* __restrict__ Wn2l,
    const float* __restrict__ nb1, const float* __restrict__ nb2) {
  __shared__ __attribute__((aligned(16))) unsigned short sTh[64 * TPITCH];
  __shared__ __attribute__((aligned(16))) unsigned short sTl[64 * TPITCH];
  const int t = threadIdx.x;
  const int nb = blockIdx.x * 64;
  const int lane = t & 63, w = t >> 6;
  const int q = lane >> 4, li = lane & 15;
  const int nrow = w * 16 + li;
  const size_t node = (size_t)nb + nrow;  // pad rows read garbage; outputs guarded

  // Preload A-fragments
  bf16x8 aH[2], aL[2], gH[2], gL[2];
#pragma unroll
  for (int ks = 0; ks < 2; ks++) {
    int k = ks * 32 + q * 8;
    aH[ks] = *(const bf16x8*)(hbh + node * 64 + k);
    aL[ks] = *(const bf16x8*)(hbl + node * 64 + k);
    const float4* ap = (const float4*)(agg + node * 64 + k);
    float4 a0 = ap[0], a1 = ap[1];
    float av[8] = {a0.x, a0.y, a0.z, a0.w, a1.x, a1.y, a1.z, a1.w};
    unsigned short* ph = (unsigned short*)&gH[ks];
    unsigned short* pl = (unsigned short*)&gL[ks];
#pragma unroll
    for (int j = 0; j < 8; j++) split2(av[j], ph[j], pl[j]);
  }

  if (t < 192) {
    int n = nb + t / 3, c = t % 3;
    if (n < N_NODES) xout[(size_t)n * 3 + c] *= nmask[n];
  }

  f32x4 acc[4];
  const f32x4 zero4 = {0.f, 0.f, 0.f, 0.f};
#pragma unroll
  for (int ct = 0; ct < 4; ct++) acc[ct] = zero4;

  // chunk h (k 0..63)
#pragma unroll
  for (int ks = 0; ks < 2; ks++) {
    int k = ks * 32 + q * 8;
    bf16x8 wH[4], wL[4];
#pragma unroll
    for (int ct = 0; ct < 4; ct++) {
      size_t wo = (size_t)(ct * 16 + li) * 128 + k;
      wH[ct] = *(const bf16x8*)(Wn1h + wo);
      wL[ct] = *(const bf16x8*)(Wn1l + wo);
    }
#pragma unroll
    for (int ct = 0; ct < 4; ct++) {
      MFMA3(aH[ks], aL[ks], wH[ct], wL[ct], acc[ct]);
    }
  }
  // chunk agg (k 64..127)
#pragma unroll
  for (int ks = 0; ks < 2; ks++) {
    int k = ks * 32 + q * 8;
    bf16x8 wH[4], wL[4];
#pragma unroll
    for (int ct = 0; ct < 4; ct++) {
      size_t wo = (size_t)(ct * 16 + li) * 128 + 64 + k;
      wH[ct] = *(const bf16x8*)(Wn1h + wo);
      wL[ct] = *(const bf16x8*)(Wn1l + wo);
    }
#pragma unroll
    for (int ct = 0; ct < 4; ct++) {
      MFMA3(gH[ks], gL[ks], wH[ct], wL[ct], acc[ct]);
    }
  }
#pragma unroll
  for (int ct = 0; ct < 4; ct++) {
    float bias = nb1[ct * 16 + li];
#pragma unroll
    for (int r = 0; r < 4; r++) {
      int nl = w * 16 + q * 4 + r;
      float v = silu_f(acc[ct][r] + bias);
      unsigned short hi, lo; split2(v, hi, lo);
      sTh[nl * TPITCH + ct * 16 + li] = hi;
      sTl[nl * TPITCH + ct * 16 + li] = lo;
    }
  }
  __syncthreads();

#pragma unroll
  for (int ct = 0; ct < 4; ct++) acc[ct] = zero4;
  {
    bf16x8 tH[2], tL[2];
#pragma unroll
    for (int ks = 0; ks < 2; ks++) {
      int kb = ks * 32 + q * 8;
      tH[ks] = *(const bf16x8*)(sTh + nrow * TPITCH + kb);
      tL[ks] = *(const bf16x8*)(sTl + nrow * TPITCH + kb);
    }
#pragma unroll
    for (int ks = 0; ks < 2; ks++) {
      int kb = ks * 32 + q * 8;
      bf16x8 wH[4], wL[4];
#pragma unroll
      for (int ct = 0; ct < 4; ct++) {
        size_t wo = (size_t)(ct * 16 + li) * 64 + kb;
        wH[ct] = *(const bf16x8*)(Wn2h + wo);
        wL[ct] = *(const bf16x8*)(Wn2l + wo);
      }
#pragma unroll
      for (int ct = 0; ct < 4; ct++) {
        MFMA3(tH[ks], tL[ks], wH[ct], wL[ct], acc[ct]);
      }
    }
  }
#pragma unroll
  for (int ct = 0; ct < 4; ct++) {
    float bias = nb2[ct * 16 + li];
#pragma unroll
    for (int r = 0; r < 4; r++) {
      int nd = nb + w * 16 + q * 4 + r;
      if (nd < N_NODES) {
        float nm = nmask[nd];
        size_t o = (size_t)nd * 64 + ct * 16 + li;
        float hv = b2f(hbh[o]) + b2f(hbl[o]);
        float v = (hv + acc[ct][r] + bias) * nm;
        unsigned short hi, lo; split2(v, hi, lo);
        hbh[o] = hi; hbl[o] = lo;
      }
    }
  }
}

// ---------------- output heads ----------------
__global__ void k_hout(const unsigned short* __restrict__ hbh,
                       const unsigned short* __restrict__ hbl,
                       const float* __restrict__ W, const float* __restrict__ b,
                       const float* __restrict__ nmask, float* __restrict__ out) {
  int id = blockIdx.x * 256 + threadIdx.x;
  if (id >= N_NODES * 16) return;
  int n = id >> 4, j = id & 15;
  float s = b[j];
#pragma unroll
  for (int k = 0; k < 64; k++) {
    float hv = b2f(hbh[(size_t)n * 64 + k]) + b2f(hbl[(size_t)n * 64 + k]);
    s += hv * W[k * 16 + j];
  }
  out[id] = s * nmask[n];
}
__global__ __launch_bounds__(256) void k_eout(const unsigned short* __restrict__ ebh,
                       const unsigned short* __restrict__ ebl,
                       const float* __restrict__ W, const float* __restrict__ b,
                       const float* __restrict__ emask, float* __restrict__ out) {
  __shared__ float sW[512];
  __shared__ float sB[8];
  int t = threadIdx.x;
  sW[t] = W[t]; sW[t + 256] = W[t + 256];
  if (t < 8) sB[t] = b[t];
  __syncthreads();
  int e = blockIdx.x * 256 + t;
  if (e >= N_EDGES) return;
  float accs[8];
#pragma unroll
  for (int j = 0; j < 8; j++) accs[j] = sB[j];
  const uint4* rh = (const uint4*)(ebh + (size_t)e * 64);
  const uint4* rl = (const uint4*)(ebl + (size_t)e * 64);
#pragma unroll
  for (int i = 0; i < 8; i++) {
    uint4 vh = rh[i], vl = rl[i];
    unsigned int uh[4] = {vh.x, vh.y, vh.z, vh.w};
    unsigned int ul[4] = {vl.x, vl.y, vl.z, vl.w};
#pragma unroll
    for (int pp = 0; pp < 4; pp++) {
      float lo = b2f((unsigned short)(uh[pp] & 0xffffu)) + b2f((unsigned short)(ul[pp] & 0xffffu));
      float hi = b2f((unsigned short)(uh[pp] >> 16)) + b2f((unsigned short)(ul[pp] >> 16));
      int k = i * 8 + pp * 2;
#pragma unroll
      for (int j = 0; j < 8; j++)
        accs[j] += lo * sW[k * 8 + j] + hi * sW[(k + 1) * 8 + j];
    }
  }
  float em = emask[e];
#pragma unroll
  for (int j = 0; j < 8; j++) out[(size_t)e * 8 + j] = accs[j] * em;
}

extern "C" void kernel_launch(void* const* d_in, const int* in_sizes, int n_in,
                              void* d_out, int out_size, void* d_ws, size_t ws_size,
                              hipStream_t stream) {
  (void)in_sizes; (void)n_in; (void)out_size; (void)ws_size;
  const float* in_h   = (const float*)d_in[0];
  const float* in_x   = (const float*)d_in[1];
  const float* in_ea  = (const float*)d_in[2];
  const float* nmask  = (const float*)d_in[3];
  const float* emask  = (const float*)d_in[4];
  const float* Wn_in  = (const float*)d_in[5];
  const float* bn_in  = (const float*)d_in[6];
  const float* Wn_out = (const float*)d_in[7];
  const float* bn_out = (const float*)d_in[8];
  const float* We_in  = (const float*)d_in[9];
  const float* be_in  = (const float*)d_in[10];
  const float* We_out = (const float*)d_in[11];
  const float* be_out = (const float*)d_in[12];
  const float* eW1    = (const float*)d_in[13];
  const float* eb1    = (const float*)d_in[14];
  const float* eW2    = (const float*)d_in[15];
  const float* eb2    = (const float*)d_in[16];
  const float* nW1    = (const float*)d_in[17];
  const float* nb1    = (const float*)d_in[18];
  const float* nW2    = (const float*)d_in[19];
  const float* nb2    = (const float*)d_in[20];
  const float* cW1    = (const float*)d_in[21];
  const float* cb1    = (const float*)d_in[22];
  const float* cW2    = (const float*)d_in[23];
  const int*   eidx   = (const int*)d_in[24];

  char* ws = (char*)d_ws;
  size_t off = 0;
  auto alloc = [&](size_t bytes) {
    size_t o = off; off = (off + bytes + 255) & ~(size_t)255; return (void*)(ws + o);
  };
  unsigned short* hbh  = (unsigned short*)alloc((size_t)N_PAD * 64 * 2);
  unsigned short* hbl  = (unsigned short*)alloc((size_t)N_PAD * 64 * 2);
  unsigned short* ebh  = (unsigned short*)alloc((size_t)N_EDGES * 64 * 2);
  unsigned short* ebl  = (unsigned short*)alloc((size_t)N_EDGES * 64 * 2);
  float* agg           = (float*)alloc((size_t)N_PAD * 64 * 4);
  float* xb0           = (float*)alloc((size_t)N_NODES * 3 * 4);
  float* xb1           = (float*)alloc((size_t)N_NODES * 3 * 4);
  unsigned short* W1h  = (unsigned short*)alloc((size_t)NLAYERS * 64 * 192 * 2);
  unsigned short* W1l  = (unsigned short*)alloc((size_t)NLAYERS * 64 * 192 * 2);
  float* w1rad         = (float*)alloc((size_t)NLAYERS * 64 * 4);
  unsigned short* W2h  = (unsigned short*)alloc((size_t)NLAYERS * 64 * 64 * 2);
  unsigned short* W2l  = (unsigned short*)alloc((size_t)NLAYERS * 64 * 64 * 2);
  unsigned short* Wch  = (unsigned short*)alloc((size_t)NLAYERS * 64 * 64 * 2);
  unsigned short* Wcl  = (unsigned short*)alloc((size_t)NLAYERS * 64 * 64 * 2);
  unsigned short* Wn1h = (unsigned short*)alloc((size_t)NLAYERS * 64 * 128 * 2);
  unsigned short* Wn1l = (unsigned short*)alloc((size_t)NLAYERS * 64 * 128 * 2);
  unsigned short* Wn2h = (unsigned short*)alloc((size_t)NLAYERS * 64 * 64 * 2);
  unsigned short* Wn2l = (unsigned short*)alloc((size_t)NLAYERS * 64 * 64 * 2);

  k_convW1<<<(NLAYERS * 64 * 192 + 255) / 256, 256, 0, stream>>>(eW1, W1h, W1l, w1rad);
  k_convT<<<(NLAYERS * 64 * 64 + 255) / 256, 256, 0, stream>>>(eW2, W2h, W2l, 64);
  k_convT<<<(NLAYERS * 64 * 64 + 255) / 256, 256, 0, stream>>>(cW1, Wch, Wcl, 64);
  k_convT<<<(NLAYERS * 64 * 128 + 255) / 256, 256, 0, stream>>>(nW1, Wn1h, Wn1l, 128);
  k_convT<<<(NLAYERS * 64 * 64 + 255) / 256, 256, 0, stream>>>(nW2, Wn2h, Wn2l, 64);

  k_h0<<<(N_NODES * 64 + 255) / 256, 256, 0, stream>>>(in_h, Wn_in, bn_in, hbh, hbl);
  k_e0<<<(N_EDGES * 64 + 255) / 256, 256, 0, stream>>>(in_ea, We_in, be_in, ebh, ebl);
  hipMemcpyAsync(xb0, in_x, (size_t)N_NODES * 3 * 4, hipMemcpyDeviceToDevice, stream);

  for (int l = 0; l < NLAYERS; l++) {
    float* xi = (l & 1) ? xb1 : xb0;
    float* xo = (l & 1) ? xb0 : xb1;
    hipMemsetAsync(agg, 0, (size_t)N_NODES * 64 * 4, stream);
    hipMemcpyAsync(xo, xi, (size_t)N_NODES * 3 * 4, hipMemcpyDeviceToDevice, stream);
    edge_kernel<<<N_EDGES / 64, 256, 0, stream>>>(
        hbh, hbl, ebh, ebl, xi, xo, agg, eidx, emask,
        W1h + (size_t)l * 64 * 192, W1l + (size_t)l * 64 * 192, w1rad + (size_t)l * 64,
        W2h + (size_t)l * 64 * 64, W2l + (size_t)l * 64 * 64,
        Wch + (size_t)l * 64 * 64, Wcl + (size_t)l * 64 * 64,
        eb1 + l * 64, eb2 + l * 64, cb1 + l * 64, cW2 + l * 64);
    node_kernel<<<(N_NODES + 63) / 64, 256, 0, stream>>>(
        hbh, hbl, agg, xo, nmask,
        Wn1h + (size_t)l * 64 * 128, Wn1l + (size_t)l * 64 * 128,
        Wn2h + (size_t)l * 64 * 64, Wn2l + (size_t)l * 64 * 64,
        nb1 + l * 64, nb2 + l * 64);
  }

  float* out = (float*)d_out;
  k_hout<<<(N_NODES * 16 + 255) / 256, 256, 0, stream>>>(hbh, hbl, Wn_out, bn_out, nmask, out);
  k_eout<<<N_EDGES / 256, 256, 0, stream>>>(ebh, ebl, We_out, be_out, emask, out + 950000);
  hipMemcpyAsync(out + 800000, xb0, (size_t)N_NODES * 3 * 4, hipMemcpyDeviceToDevice, stream);
}